// Round 2
// baseline (894.382 us; speedup 1.0000x reference)
//
#include <hip/hip_runtime.h>
#include <hip/hip_cooperative_groups.h>

namespace cg = cooperative_groups;

#define NN 50000
#define NE 600000
#define DD 128
#define NPAD 50048      // 782 * 64
#define NTILE 782       // NPAD / 64
#define NCHUNK 196      // ceil(NN / 256)
#define SCAN_BLOCKS 49  // fallback path: ceil(50000/1024)

typedef __attribute__((ext_vector_type(8))) short bf16x8;
typedef __attribute__((ext_vector_type(4))) float f32x4;

__device__ __forceinline__ float bf2f(unsigned int u16) {
    union { unsigned int i; float f; } v; v.i = u16 << 16; return v.f;
}
__device__ __forceinline__ unsigned short f2bf(float f) {
    union { float f; unsigned int i; } v; v.f = f;
    unsigned int i = v.i + 0x7FFFu + ((v.i >> 16) & 1u);
    return (unsigned short)(i >> 16);
}
__device__ __forceinline__ float wred64(float v) {
    #pragma unroll
    for (int o = 32; o; o >>= 1) v += __shfl_xor(v, o, 64);
    return v;
}
__device__ __forceinline__ int tame16(unsigned int u) {
    int e = (int)((u >> 7) & 0xFF);
    return (e >= 100 && e <= 133) ? 1 : 0;
}

// ---------------- fused phase bodies ----------------

// wave-per-node aggregation (v2 structure: index-in-register + shfl broadcast,
// dual-row uint2 gathers, zero-row padding at index NN)
__device__ __forceinline__ void agg_phase(
    const int* __restrict__ offs, const int* __restrict__ eidx,
    const uint2* __restrict__ featu2, const void* __restrict__ noise,
    const int f_nb, uint2* __restrict__ aggu2,
    const int wvg, const int nwv, const int lane) {
    const int c = lane & 31;
    const int h = lane >> 5;
    for (int node = wvg; node < NN; node += nwv) {
        float a0, a1, a2, a3;
        if (h == 0) {
            const uint2 s = featu2[(size_t)node * 32 + c];
            a0 = bf2f(s.x & 0xFFFFu); a1 = bf2f(s.x >> 16);
            a2 = bf2f(s.y & 0xFFFFu); a3 = bf2f(s.y >> 16);
        } else {
            if (f_nb) {
                const uint2 n = ((const uint2*)noise)[(size_t)node * 32 + c];
                a0 = bf2f(n.x & 0xFFFFu); a1 = bf2f(n.x >> 16);
                a2 = bf2f(n.y & 0xFFFFu); a3 = bf2f(n.y >> 16);
            } else {
                const float4 n = ((const float4*)noise)[(size_t)node * 32 + c];
                a0 = n.x; a1 = n.y; a2 = n.z; a3 = n.w;
            }
        }
        const int e0 = offs[node];
        const int cnt = offs[node + 1] - e0;
        for (int base = 0; base < cnt; base += 64) {
            const int rem = cnt - base;
            int myi = NN;
            if (lane < rem) myi = eidx[e0 + base + lane];
            const int pairs = (rem < 64 ? rem + 1 : 64) >> 1;
            const int pb = (pairs + 7) & ~7;
            for (int p = 0; p < pb; p += 8) {
                uint2 u[8];
                #pragma unroll
                for (int q = 0; q < 8; ++q) {
                    const int s = __shfl(myi, 2 * (p + q) + h, 64);
                    u[q] = featu2[(size_t)s * 32 + c];
                }
                #pragma unroll
                for (int q = 0; q < 8; ++q) {
                    a0 += bf2f(u[q].x & 0xFFFFu); a1 += bf2f(u[q].x >> 16);
                    a2 += bf2f(u[q].y & 0xFFFFu); a3 += bf2f(u[q].y >> 16);
                }
            }
        }
        a0 += __shfl_xor(a0, 32, 64);
        a1 += __shfl_xor(a1, 32, 64);
        a2 += __shfl_xor(a2, 32, 64);
        a3 += __shfl_xor(a3, 32, 64);
        if (h == 0) {
            uint2 o;
            o.x = (unsigned int)f2bf(a0) | ((unsigned int)f2bf(a1) << 16);
            o.y = (unsigned int)f2bf(a2) | ((unsigned int)f2bf(a3) << 16);
            aggu2[(size_t)node * 32 + c] = o;
        }
    }
}

// MFMA GEMM tile phase. W staged once into LDS, then grid-stride over tiles.
template<bool LAYER1>
__device__ __forceinline__ void gemm_phase(
    const unsigned short* __restrict__ aggb,
    const unsigned short* __restrict__ Wb,
    const unsigned short* __restrict__ bb,
    unsigned short* __restrict__ featb, float* __restrict__ outf,
    unsigned short* Wl, unsigned short* bl,
    const int b, const int t, const int ngrid) {
    #pragma unroll
    for (int i = 0; i < 8; ++i) {
        const int idx8 = t + i * 256;
        const int base = idx8 * 8;
        const int row = base >> 7, col = base & 127;
        *(uint4*)&Wl[row * 136 + col] = ((const uint4*)Wb)[idx8];
    }
    if (t < 128) bl[t] = bb[t];
    __syncthreads();

    const int lane = t & 63;
    const int w = t >> 6;
    const int n15 = lane & 15;
    const int quad = lane >> 4;

    for (int tile = b; tile < NTILE; tile += ngrid) {
        const int rbase = tile * 64 + w * 16;
        bf16x8 af[4];
        #pragma unroll
        for (int kc = 0; kc < 4; ++kc)
            af[kc] = *(const bf16x8*)&aggb[(size_t)(rbase + n15) * DD + kc * 32 + quad * 8];

        float h[32];
        #pragma unroll
        for (int nt = 0; nt < 8; ++nt) {
            f32x4 acc = {0.f, 0.f, 0.f, 0.f};
            #pragma unroll
            for (int kc = 0; kc < 4; ++kc) {
                const bf16x8 bfr =
                    *(const bf16x8*)&Wl[(nt * 16 + n15) * 136 + kc * 32 + quad * 8];
                acc = __builtin_amdgcn_mfma_f32_16x16x32_bf16(af[kc], bfr, acc, 0, 0, 0);
            }
            const float bj = bf2f((unsigned int)bl[nt * 16 + n15]);
            #pragma unroll
            for (int r = 0; r < 4; ++r) h[nt * 4 + r] = acc[r] + bj;
        }

        if (LAYER1) {
            const float S = 1.0507009873554805f, AL = 1.6732632423543772f;
            float ss[4] = {0.f, 0.f, 0.f, 0.f};
            #pragma unroll
            for (int nt = 0; nt < 8; ++nt)
                #pragma unroll
                for (int r = 0; r < 4; ++r) {
                    float v = h[nt * 4 + r];
                    v = v > 0.f ? S * v : S * AL * expm1f(v);
                    h[nt * 4 + r] = v;
                    ss[r] += v * v;
                }
            #pragma unroll
            for (int r = 0; r < 4; ++r) {
                #pragma unroll
                for (int off = 1; off < 16; off <<= 1)
                    ss[r] += __shfl_xor(ss[r], off, 64);
            }
            #pragma unroll
            for (int r = 0; r < 4; ++r) {
                const float nr = sqrtf(ss[r]);
                const float sc = nr > 1.f ? 1.f / nr : 1.f;
                const int row = rbase + quad * 4 + r;
                if (row < NN) {
                    #pragma unroll
                    for (int nt = 0; nt < 8; ++nt)
                        featb[(size_t)row * DD + nt * 16 + n15] =
                            f2bf(h[nt * 4 + r] * sc);
                }
            }
        } else {
            #pragma unroll
            for (int r = 0; r < 4; ++r) {
                const int row = rbase + quad * 4 + r;
                if (row < NN) {
                    #pragma unroll
                    for (int nt = 0; nt < 8; ++nt)
                        outf[(size_t)row * DD + nt * 16 + n15] = h[nt * 4 + r];
                }
            }
        }
    }
}

// ---------------- the fused cooperative kernel ----------------
__global__ __launch_bounds__(256, 4) void fused_k(
    const void* __restrict__ x, const int* __restrict__ ei,
    const void* __restrict__ W1, const void* __restrict__ b1,
    const void* __restrict__ W2, const void* __restrict__ b2,
    const void* __restrict__ n1, const void* __restrict__ n2,
    unsigned short* __restrict__ aggb,
    unsigned short* __restrict__ W1b, unsigned short* __restrict__ b1b,
    unsigned short* __restrict__ W2b, unsigned short* __restrict__ b2b,
    int* __restrict__ deg, int* __restrict__ offs, int* __restrict__ cursor,
    int* __restrict__ bsum, int* __restrict__ eidx,
    unsigned int* __restrict__ featu) {
    cg::grid_group grid = cg::this_grid();
    __shared__ unsigned short Wl[128 * 136];
    __shared__ unsigned short bl[128];
    __shared__ int flags_s[4];
    __shared__ int wsum[4], wbase[4];
    __shared__ int tot_s;

    const int t = threadIdx.x;
    const int b = blockIdx.x;
    const int ngrid = gridDim.x;
    const int lane = t & 63;
    const int wv = t >> 6;
    const int tid = b * 256 + t;
    const int nthr = ngrid * 256;
    const int wvg = b * 4 + wv;
    const int nwv = ngrid * 4;

    // ---- local flag probe (every block; tiny, L2-broadcast) ----
    if (wv == 0) {
        int nz = 0;
        #pragma unroll
        for (int i = 0; i < 4; ++i) nz |= ei[2 * (lane * 4 + i) + 1];
        int tx = tame16(((const unsigned int*)x)[lane] & 0xFFFFu);
        int tw = tame16(((const unsigned int*)W1)[lane] & 0xFFFFu);
        int tn = tame16(((const unsigned int*)n1)[lane] & 0xFFFFu);
        #pragma unroll
        for (int o = 32; o; o >>= 1) {
            nz |= __shfl_xor(nz, o, 64);
            tx += __shfl_xor(tx, o, 64);
            tw += __shfl_xor(tw, o, 64);
            tn += __shfl_xor(tn, o, 64);
        }
        if (lane == 0) {
            flags_s[0] = (nz == 0) ? 1 : 0;
            flags_s[1] = (tx >= 48) ? 1 : 0;
            flags_s[2] = (tw >= 48) ? 1 : 0;
            flags_s[3] = (tn >= 48) ? 1 : 0;
        }
    }
    __syncthreads();
    const int f_e64 = flags_s[0], f_xb = flags_s[1];
    const int f_wb = flags_s[2], f_nb = flags_s[3];

    // ---- P0: convert W, zero deg, prep featu (all independent) ----
    for (int i = tid; i < DD * DD; i += nthr) {
        if (f_wb) {
            W1b[i] = ((const unsigned short*)W1)[i];
            W2b[i] = ((const unsigned short*)W2)[i];
            if (i < DD) { b1b[i] = ((const unsigned short*)b1)[i];
                          b2b[i] = ((const unsigned short*)b2)[i]; }
        } else {
            W1b[i] = f2bf(((const float*)W1)[i]);
            W2b[i] = f2bf(((const float*)W2)[i]);
            if (i < DD) { b1b[i] = f2bf(((const float*)b1)[i]);
                          b2b[i] = f2bf(((const float*)b2)[i]); }
        }
    }
    for (int i = tid; i < NN; i += nthr) deg[i] = 0;
    for (int row = wvg; row <= NN; row += nwv) {
        if (row == NN) { featu[(size_t)NN * 64 + lane] = 0u; continue; }
        float v0, v1;
        if (f_xb) {
            const unsigned int px = ((const unsigned int*)x)[(size_t)row * 64 + lane];
            v0 = bf2f(px & 0xFFFFu); v1 = bf2f(px >> 16);
        } else {
            const float2 px = ((const float2*)x)[(size_t)row * 64 + lane];
            v0 = px.x; v1 = px.y;
        }
        const float ss = wred64(v0 * v0 + v1 * v1);
        const float nrm = sqrtf(ss);
        const float sc = nrm > 1.0f ? 1.0f / nrm : 1.0f;
        featu[(size_t)row * 64 + lane] =
            (unsigned int)f2bf(v0 * sc) | ((unsigned int)f2bf(v1 * sc) << 16);
    }
    grid.sync();

    // ---- P1: histogram of in-degrees ----
    for (int e = tid; e < NE; e += nthr) {
        const int d = f_e64 ? (int)((const long long*)ei)[NE + e] : ei[NE + e];
        atomicAdd(&deg[d], 1);
    }
    grid.sync();

    // ---- P2a: per-chunk (256-wide) exclusive scan ----
    for (int ch = b; ch < NCHUNK; ch += ngrid) {
        const int i = ch * 256 + t;
        const int v = (i < NN) ? deg[i] : 0;
        int incl = v;
        #pragma unroll
        for (int off = 1; off < 64; off <<= 1) {
            int tt = __shfl_up(incl, off, 64);
            if (lane >= off) incl += tt;
        }
        if (lane == 63) wsum[wv] = incl;
        __syncthreads();
        if (t < 4) {
            int s = 0;
            for (int k = 0; k < t; ++k) s += wsum[k];
            wbase[t] = s;
            if (t == 3) tot_s = s + wsum[3];
        }
        __syncthreads();
        if (i < NN) offs[i] = wbase[wv] + incl - v;
        if (t == 0) bsum[ch] = tot_s;
        __syncthreads();
    }
    grid.sync();

    // ---- P2b: scan the 196 chunk totals (block 0) ----
    if (b == 0) {
        const int v = (t < NCHUNK) ? bsum[t] : 0;
        int incl = v;
        #pragma unroll
        for (int off = 1; off < 64; off <<= 1) {
            int tt = __shfl_up(incl, off, 64);
            if (lane >= off) incl += tt;
        }
        if (lane == 63) wsum[wv] = incl;
        __syncthreads();
        if (t < 4) {
            int s = 0;
            for (int k = 0; k < t; ++k) s += wsum[k];
            wbase[t] = s;
        }
        __syncthreads();
        if (t < NCHUNK) bsum[t] = wbase[wv] + incl - v;
    }
    grid.sync();

    // ---- P2c: add chunk base, init cursor ----
    for (int ch = b; ch < NCHUNK; ch += ngrid) {
        const int i = ch * 256 + t;
        if (i < NN) {
            const int o = offs[i] + bsum[ch];
            offs[i] = o;
            cursor[i] = o;
        }
    }
    if (b == 0 && t == 0) offs[NN] = NE;
    grid.sync();

    // ---- P3: fill CSR adjacency ----
    for (int e = tid; e < NE; e += nthr) {
        int s, d;
        if (f_e64) {
            const long long* e64 = (const long long*)ei;
            s = (int)e64[e]; d = (int)e64[NE + e];
        } else {
            s = ei[e]; d = ei[NE + e];
        }
        const int pos = atomicAdd(&cursor[d], 1);
        eidx[pos] = s;
    }
    grid.sync();

    // ---- P4: aggregate layer 1 ----
    agg_phase(offs, eidx, (const uint2*)featu, n1, f_nb, (uint2*)aggb,
              wvg, nwv, lane);
    grid.sync();

    // ---- P5: GEMM layer 1 (SELU + row clip -> featu bf16) ----
    gemm_phase<true>(aggb, W1b, b1b, (unsigned short*)featu, nullptr,
                     Wl, bl, b, t, ngrid);
    grid.sync();

    // ---- P6: aggregate layer 2 ----
    agg_phase(offs, eidx, (const uint2*)featu, n2, f_nb, (uint2*)aggb,
              wvg, nwv, lane);
    grid.sync();

    // ---- P7: GEMM layer 2 (f32 out over d_out) ----
    gemm_phase<false>(aggb, W2b, b2b, nullptr, (float*)featu,
                      Wl, bl, b, t, ngrid);
}

// ---------------- fallback path (verified round-1 kernels) ----------------

__global__ void probe_k(const int* __restrict__ ei,
                        const unsigned int* __restrict__ xw,
                        const unsigned int* __restrict__ w1w,
                        const unsigned int* __restrict__ nzw,
                        int* __restrict__ flags) {
    const int lane = threadIdx.x;
    int nz = 0;
    #pragma unroll
    for (int i = 0; i < 4; ++i) nz |= ei[2 * (lane * 4 + i) + 1];
    int tx = tame16(xw[lane] & 0xFFFFu);
    int tw = tame16(w1w[lane] & 0xFFFFu);
    int tn = tame16(nzw[lane] & 0xFFFFu);
    #pragma unroll
    for (int o = 32; o; o >>= 1) {
        nz |= __shfl_xor(nz, o, 64);
        tx += __shfl_xor(tx, o, 64);
        tw += __shfl_xor(tw, o, 64);
        tn += __shfl_xor(tn, o, 64);
    }
    if (lane == 0) {
        flags[0] = (nz == 0) ? 1 : 0;
        flags[1] = (tx >= 48) ? 1 : 0;
        flags[2] = (tw >= 48) ? 1 : 0;
        flags[3] = (tn >= 48) ? 1 : 0;
    }
}

__global__ __launch_bounds__(256) void convert_k(
    const void* __restrict__ W1, const void* __restrict__ b1,
    const void* __restrict__ W2, const void* __restrict__ b2,
    const int* __restrict__ flags,
    unsigned short* __restrict__ W1b, unsigned short* __restrict__ b1b,
    unsigned short* __restrict__ W2b, unsigned short* __restrict__ b2b) {
    const int i = blockIdx.x * blockDim.x + threadIdx.x;
    if (i >= DD * DD) return;
    if (flags[2]) {
        W1b[i] = ((const unsigned short*)W1)[i];
        W2b[i] = ((const unsigned short*)W2)[i];
        if (i < DD) { b1b[i] = ((const unsigned short*)b1)[i];
                      b2b[i] = ((const unsigned short*)b2)[i]; }
    } else {
        W1b[i] = f2bf(((const float*)W1)[i]);
        W2b[i] = f2bf(((const float*)W2)[i]);
        if (i < DD) { b1b[i] = f2bf(((const float*)b1)[i]);
                      b2b[i] = f2bf(((const float*)b2)[i]); }
    }
}

__global__ __launch_bounds__(256) void hist_k(
    const int* __restrict__ ei, const int* __restrict__ flags,
    int* __restrict__ deg) {
    const int e = blockIdx.x * blockDim.x + threadIdx.x;
    if (e >= NE) return;
    const int d = flags[0] ? (int)((const long long*)ei)[NE + e] : ei[NE + e];
    atomicAdd(&deg[d], 1);
}

__global__ __launch_bounds__(1024) void scan1_k(
    const int* __restrict__ deg, int* __restrict__ offs,
    int* __restrict__ bsum) {
    __shared__ int wsum[16];
    __shared__ int wbase[16];
    __shared__ int tot_s;
    const int tid = threadIdx.x, lane = tid & 63, wv = tid >> 6;
    const int i = blockIdx.x * 1024 + tid;
    const int v = (i < NN) ? deg[i] : 0;
    int incl = v;
    #pragma unroll
    for (int off = 1; off < 64; off <<= 1) {
        int t = __shfl_up(incl, off, 64);
        if (lane >= off) incl += t;
    }
    if (lane == 63) wsum[wv] = incl;
    __syncthreads();
    if (wv == 0 && lane < 16) {
        const int wv_v = wsum[lane];
        int wincl = wv_v;
        #pragma unroll
        for (int off = 1; off < 16; off <<= 1) {
            int t = __shfl_up(wincl, off, 64);
            if (lane >= off) wincl += t;
        }
        wbase[lane] = wincl - wv_v;
        if (lane == 15) tot_s = wincl;
    }
    __syncthreads();
    if (i < NN) offs[i] = wbase[wv] + incl - v;
    if (tid == 0) bsum[blockIdx.x] = tot_s;
}

__global__ __launch_bounds__(1024) void scan2_k(
    int* __restrict__ offs, int* __restrict__ cursor,
    const int* __restrict__ bsum) {
    __shared__ int base_s;
    const int tid = threadIdx.x;
    if (tid < 64) {
        const int v = (tid < SCAN_BLOCKS) ? bsum[tid] : 0;
        int incl = v;
        #pragma unroll
        for (int off = 1; off < 64; off <<= 1) {
            int t = __shfl_up(incl, off, 64);
            if (tid >= off) incl += t;
        }
        if (tid == blockIdx.x) base_s = incl - v;
    }
    __syncthreads();
    const int i = blockIdx.x * 1024 + tid;
    if (i < NN) {
        const int o = offs[i] + base_s;
        offs[i] = o;
        cursor[i] = o;
    }
    if (blockIdx.x == 0 && tid == 0) offs[NN] = NE;
}

__global__ __launch_bounds__(256) void fill_k(
    const int* __restrict__ ei, const int* __restrict__ flags,
    int* __restrict__ cursor, int* __restrict__ eidx) {
    const int e = blockIdx.x * blockDim.x + threadIdx.x;
    if (e >= NE) return;
    int s, d;
    if (flags[0]) {
        const long long* e64 = (const long long*)ei;
        s = (int)e64[e]; d = (int)e64[NE + e];
    } else {
        s = ei[e]; d = ei[NE + e];
    }
    const int pos = atomicAdd(&cursor[d], 1);
    eidx[pos] = s;
}

__global__ __launch_bounds__(256) void prep_k(
    const void* __restrict__ x, const int* __restrict__ flags,
    unsigned int* __restrict__ featu) {
    const int row = (blockIdx.x * blockDim.x + threadIdx.x) >> 6;
    const int lane = threadIdx.x & 63;
    if (row > NN) return;
    if (row == NN) { featu[(size_t)NN * 64 + lane] = 0u; return; }
    float v0, v1;
    if (flags[1]) {
        const unsigned int px = ((const unsigned int*)x)[(size_t)row * 64 + lane];
        v0 = bf2f(px & 0xFFFFu); v1 = bf2f(px >> 16);
    } else {
        const float2 px = ((const float2*)x)[(size_t)row * 64 + lane];
        v0 = px.x; v1 = px.y;
    }
    const float ss = wred64(v0 * v0 + v1 * v1);
    const float nrm = sqrtf(ss);
    const float sc = nrm > 1.0f ? 1.0f / nrm : 1.0f;
    featu[(size_t)row * 64 + lane] =
        (unsigned int)f2bf(v0 * sc) | ((unsigned int)f2bf(v1 * sc) << 16);
}

__global__ __launch_bounds__(256) void agg_k(
    const int* __restrict__ offs, const int* __restrict__ eidx,
    const uint2* __restrict__ featu2, const void* __restrict__ noise,
    const int* __restrict__ flags, uint2* __restrict__ aggu2) {
    const int node = (blockIdx.x * blockDim.x + threadIdx.x) >> 6;
    const int lane = threadIdx.x & 63;
    if (node >= NN) return;
    agg_phase(offs, eidx, featu2, noise, flags[3], aggu2, node, 1 << 30, lane);
}

template<bool LAYER1>
__global__ __launch_bounds__(256) void gemm_k(
    const unsigned short* __restrict__ aggb,
    const unsigned short* __restrict__ Wb,
    const unsigned short* __restrict__ bb,
    unsigned short* __restrict__ featb,
    float* __restrict__ outf) {
    __shared__ unsigned short Wl[128 * 136];
    __shared__ unsigned short bl[128];
    // single-tile via huge stride
    gemm_phase<LAYER1>(aggb, Wb, bb, featb, outf, Wl, bl,
                       blockIdx.x, threadIdx.x, 1 << 30);
}

extern "C" void kernel_launch(void* const* d_in, const int* in_sizes, int n_in,
                              void* d_out, int out_size, void* d_ws, size_t ws_size,
                              hipStream_t stream) {
    const void* x  = d_in[0];
    const int*  ei = (const int*)d_in[1];
    const void* W1 = d_in[2];
    const void* b1 = d_in[3];
    const void* W2 = d_in[4];
    const void* b2 = d_in[5];
    const void* n1 = d_in[6];
    const void* n2 = d_in[7];

    // ws layout (~16 MB)
    unsigned short* aggb = (unsigned short*)d_ws;        // NPAD*128 bf16
    unsigned short* W1b  = aggb + (size_t)NPAD * DD;
    unsigned short* b1b  = W1b + DD * DD;
    unsigned short* W2b  = b1b + DD;
    unsigned short* b2b  = W2b + DD * DD;
    int* flags  = (int*)(b2b + DD);
    int* deg    = flags + 4;
    int* offs   = deg + NN;
    int* cursor = offs + NN + 1;
    int* bsum   = cursor + NN;
    int* eidx   = bsum + 256;
    unsigned int* featu = (unsigned int*)d_out;

    // size the cooperative grid once (occupancy-checked)
    static int grid_blocks = 0;
    if (grid_blocks == 0) {
        int maxB = 0;
        if (hipOccupancyMaxActiveBlocksPerMultiprocessor(&maxB, fused_k, 256, 0)
                != hipSuccess || maxB <= 0)
            grid_blocks = -1;
        else
            grid_blocks = (maxB * 256 < 1024) ? maxB * 256 : 1024;
        if (grid_blocks < NTILE && grid_blocks > 0 && grid_blocks < NCHUNK)
            grid_blocks = -1;  // (defensive; phases need >=196 only via loops, keep sane)
    }

    bool coop_ok = false;
    if (grid_blocks > 0) {
        void* args[] = {
            (void*)&x, (void*)&ei, (void*)&W1, (void*)&b1, (void*)&W2,
            (void*)&b2, (void*)&n1, (void*)&n2,
            (void*)&aggb, (void*)&W1b, (void*)&b1b, (void*)&W2b, (void*)&b2b,
            (void*)&deg, (void*)&offs, (void*)&cursor, (void*)&bsum,
            (void*)&eidx, (void*)&featu};
        hipError_t err = hipLaunchCooperativeKernel(
            (const void*)fused_k, dim3(grid_blocks), dim3(256), args, 0, stream);
        if (err == hipSuccess) coop_ok = true;
        else { (void)hipGetLastError(); grid_blocks = -1; }
    }

    if (!coop_ok) {
        // verified multi-kernel fallback
        probe_k<<<1, 64, 0, stream>>>(ei, (const unsigned int*)x,
                                      (const unsigned int*)W1,
                                      (const unsigned int*)n1, flags);
        convert_k<<<(DD * DD + 255) / 256, 256, 0, stream>>>(W1, b1, W2, b2, flags,
                                                             W1b, b1b, W2b, b2b);
        hipMemsetAsync(deg, 0, NN * sizeof(int), stream);
        hist_k<<<(NE + 255) / 256, 256, 0, stream>>>(ei, flags, deg);
        scan1_k<<<SCAN_BLOCKS, 1024, 0, stream>>>(deg, offs, bsum);
        scan2_k<<<SCAN_BLOCKS, 1024, 0, stream>>>(offs, cursor, bsum);
        fill_k<<<(NE + 255) / 256, 256, 0, stream>>>(ei, flags, cursor, eidx);
        prep_k<<<((NN + 1) * 64 + 255) / 256, 256, 0, stream>>>(x, flags, featu);
        agg_k<<<(NN * 64) / 256, 256, 0, stream>>>(offs, eidx, (const uint2*)featu,
                                                   n1, flags, (uint2*)aggb);
        gemm_k<true><<<NPAD / 64, 256, 0, stream>>>(aggb, W1b, b1b,
                                                    (unsigned short*)featu, nullptr);
        agg_k<<<(NN * 64) / 256, 256, 0, stream>>>(offs, eidx, (const uint2*)featu,
                                                   n2, flags, (uint2*)aggb);
        gemm_k<false><<<NPAD / 64, 256, 0, stream>>>(aggb, W2b, b2b, nullptr,
                                                     (float*)d_out);
    }
}

// Round 3
// 281.303 us; speedup vs baseline: 3.1794x; 3.1794x over previous
//
#include <hip/hip_runtime.h>

#define NN 50000
#define NE 600000
#define DD 128
#define NPAD 50048      // 782 * 64
#define NTILE 782       // NPAD / 64
#define SETUP_BLOCKS 12501   // ceil((NN+1) waves / 4 waves-per-block)
#define EDGE_BLOCKS 2344     // ceil(NE / 256)
#define SCAN_BLOCKS 49       // ceil(NN / 1024)

typedef __attribute__((ext_vector_type(8))) short bf16x8;
typedef __attribute__((ext_vector_type(4))) float f32x4;

__device__ __forceinline__ float bf2f(unsigned int u16) {
    union { unsigned int i; float f; } v; v.i = u16 << 16; return v.f;
}
__device__ __forceinline__ unsigned short f2bf(float f) {
    union { float f; unsigned int i; } v; v.f = f;
    unsigned int i = v.i + 0x7FFFu + ((v.i >> 16) & 1u);
    return (unsigned short)(i >> 16);
}
__device__ __forceinline__ float wred64(float v) {
    #pragma unroll
    for (int o = 32; o; o >>= 1) v += __shfl_xor(v, o, 64);
    return v;
}
__device__ __forceinline__ int tame16(unsigned int u) {
    int e = (int)((u >> 7) & 0xFF);
    return (e >= 100 && e <= 133) ? 1 : 0;
}

// ---- per-block inline flag probes (L2-broadcast reads, ~0.5 us cold) ----

// edges-are-int64 flag: odd int32 words of first 512 are all zero
__device__ __forceinline__ int probe_e64(const int* __restrict__ ei, int t,
                                         int* f_s) {
    if (t < 64) {
        int nz = 0;
        #pragma unroll
        for (int i = 0; i < 4; ++i) nz |= ei[2 * (t * 4 + i) + 1];
        #pragma unroll
        for (int o = 32; o; o >>= 1) nz |= __shfl_xor(nz, o, 64);
        if (t == 0) *f_s = (nz == 0) ? 1 : 0;
    }
    __syncthreads();
    return *f_s;
}

// buffer-is-bf16 flag: low halves of first 64 words look like bf16
__device__ __forceinline__ int probe_bf16(const unsigned int* __restrict__ p,
                                          int t, int* f_s) {
    if (t < 64) {
        int tc = tame16(p[t] & 0xFFFFu);
        #pragma unroll
        for (int o = 32; o; o >>= 1) tc += __shfl_xor(tc, o, 64);
        if (t == 0) *f_s = (tc >= 48) ? 1 : 0;
    }
    __syncthreads();
    return *f_s;
}

// ---------------- phase bodies (verified round-1 hot loops) ----------------

__device__ __forceinline__ void agg_phase(
    const int* __restrict__ offs, const int* __restrict__ eidx,
    const uint2* __restrict__ featu2, const void* __restrict__ noise,
    const int f_nb, uint2* __restrict__ aggu2,
    const int node, const int lane) {
    const int c = lane & 31;
    const int h = lane >> 5;
    float a0, a1, a2, a3;
    if (h == 0) {
        const uint2 s = featu2[(size_t)node * 32 + c];
        a0 = bf2f(s.x & 0xFFFFu); a1 = bf2f(s.x >> 16);
        a2 = bf2f(s.y & 0xFFFFu); a3 = bf2f(s.y >> 16);
    } else {
        if (f_nb) {
            const uint2 n = ((const uint2*)noise)[(size_t)node * 32 + c];
            a0 = bf2f(n.x & 0xFFFFu); a1 = bf2f(n.x >> 16);
            a2 = bf2f(n.y & 0xFFFFu); a3 = bf2f(n.y >> 16);
        } else {
            const float4 n = ((const float4*)noise)[(size_t)node * 32 + c];
            a0 = n.x; a1 = n.y; a2 = n.z; a3 = n.w;
        }
    }
    const int e0 = offs[node];
    const int cnt = offs[node + 1] - e0;
    for (int base = 0; base < cnt; base += 64) {
        const int rem = cnt - base;
        int myi = NN;
        if (lane < rem) myi = eidx[e0 + base + lane];
        const int pairs = (rem < 64 ? rem + 1 : 64) >> 1;
        const int pb = (pairs + 7) & ~7;
        for (int p = 0; p < pb; p += 8) {
            uint2 u[8];
            #pragma unroll
            for (int q = 0; q < 8; ++q) {
                const int s = __shfl(myi, 2 * (p + q) + h, 64);
                u[q] = featu2[(size_t)s * 32 + c];
            }
            #pragma unroll
            for (int q = 0; q < 8; ++q) {
                a0 += bf2f(u[q].x & 0xFFFFu); a1 += bf2f(u[q].x >> 16);
                a2 += bf2f(u[q].y & 0xFFFFu); a3 += bf2f(u[q].y >> 16);
            }
        }
    }
    a0 += __shfl_xor(a0, 32, 64);
    a1 += __shfl_xor(a1, 32, 64);
    a2 += __shfl_xor(a2, 32, 64);
    a3 += __shfl_xor(a3, 32, 64);
    if (h == 0) {
        uint2 o;
        o.x = (unsigned int)f2bf(a0) | ((unsigned int)f2bf(a1) << 16);
        o.y = (unsigned int)f2bf(a2) | ((unsigned int)f2bf(a3) << 16);
        aggu2[(size_t)node * 32 + c] = o;
    }
}

// ---------------- kernels (8 dispatches total) ----------------

// D1: probe + W/b convert + zero(deg,pf) + prep featu (row NN = zero row)
__global__ __launch_bounds__(256) void setup_k(
    const void* __restrict__ x,
    const void* __restrict__ W1, const void* __restrict__ b1,
    const void* __restrict__ W2, const void* __restrict__ b2,
    unsigned short* __restrict__ W1b, unsigned short* __restrict__ b1b,
    unsigned short* __restrict__ W2b, unsigned short* __restrict__ b2b,
    int* __restrict__ deg, int* __restrict__ pf,
    unsigned int* __restrict__ featu) {
    __shared__ int fx_s, fw_s;
    const int t = threadIdx.x;
    if (t < 64) {
        int tx = tame16(((const unsigned int*)x)[t] & 0xFFFFu);
        int tw = tame16(((const unsigned int*)W1)[t] & 0xFFFFu);
        #pragma unroll
        for (int o = 32; o; o >>= 1) {
            tx += __shfl_xor(tx, o, 64);
            tw += __shfl_xor(tw, o, 64);
        }
        if (t == 0) { fx_s = (tx >= 48) ? 1 : 0; fw_s = (tw >= 48) ? 1 : 0; }
    }
    __syncthreads();
    const int f_xb = fx_s, f_wb = fw_s;
    const int b = blockIdx.x;
    const int tid = b * 256 + t;
    const int nthr = gridDim.x * 256;

    // W/b conversion (only first 16384 global threads iterate)
    for (int i = tid; i < DD * DD; i += nthr) {
        if (f_wb) {
            W1b[i] = ((const unsigned short*)W1)[i];
            W2b[i] = ((const unsigned short*)W2)[i];
            if (i < DD) { b1b[i] = ((const unsigned short*)b1)[i];
                          b2b[i] = ((const unsigned short*)b2)[i]; }
        } else {
            W1b[i] = f2bf(((const float*)W1)[i]);
            W2b[i] = f2bf(((const float*)W2)[i]);
            if (i < DD) { b1b[i] = f2bf(((const float*)b1)[i]);
                          b2b[i] = f2bf(((const float*)b2)[i]); }
        }
    }
    // zero deg + scan publish flags
    for (int i = tid; i < NN + 64; i += nthr) {
        if (i < NN) deg[i] = 0; else pf[i - NN] = 0;
    }
    // prep: one wave per row; row NN = zero padding row
    const int lane = t & 63;
    const int wv = t >> 6;
    const int nwv = gridDim.x * 4;
    for (int row = b * 4 + wv; row <= NN; row += nwv) {
        if (row == NN) { featu[(size_t)NN * 64 + lane] = 0u; continue; }
        float v0, v1;
        if (f_xb) {
            const unsigned int px = ((const unsigned int*)x)[(size_t)row * 64 + lane];
            v0 = bf2f(px & 0xFFFFu); v1 = bf2f(px >> 16);
        } else {
            const float2 px = ((const float2*)x)[(size_t)row * 64 + lane];
            v0 = px.x; v1 = px.y;
        }
        const float ss = wred64(v0 * v0 + v1 * v1);
        const float nrm = sqrtf(ss);
        const float sc = nrm > 1.0f ? 1.0f / nrm : 1.0f;
        featu[(size_t)row * 64 + lane] =
            (unsigned int)f2bf(v0 * sc) | ((unsigned int)f2bf(v1 * sc) << 16);
    }
}

// D2: in-degree histogram
__global__ __launch_bounds__(256) void hist_k(
    const int* __restrict__ ei, int* __restrict__ deg) {
    __shared__ int f_s;
    const int f_e64 = probe_e64(ei, threadIdx.x, &f_s);
    const int e = blockIdx.x * 256 + threadIdx.x;
    if (e >= NE) return;
    const int d = f_e64 ? (int)((const long long*)ei)[NE + e] : ei[NE + e];
    atomicAdd(&deg[d], 1);
}

// D3: single-dispatch exclusive scan (49 blocks publish totals via
// device-scope atomics, then all-wait-all; 49 blocks always co-resident)
__global__ __launch_bounds__(1024) void scan_k(
    const int* __restrict__ deg, int* __restrict__ offs,
    int* __restrict__ cursor, int* __restrict__ pf) {
    __shared__ int wsum[16];
    __shared__ int wbase[16];
    __shared__ int base_s;
    const int tid = threadIdx.x, lane = tid & 63, wv = tid >> 6;
    const int b = blockIdx.x;
    const int i = b * 1024 + tid;
    const int v = (i < NN) ? deg[i] : 0;
    int incl = v;
    #pragma unroll
    for (int off = 1; off < 64; off <<= 1) {
        int t = __shfl_up(incl, off, 64);
        if (lane >= off) incl += t;
    }
    if (lane == 63) wsum[wv] = incl;
    __syncthreads();
    if (wv == 0 && lane < 16) {
        const int wv_v = wsum[lane];
        int wincl = wv_v;
        #pragma unroll
        for (int off = 1; off < 16; off <<= 1) {
            int t = __shfl_up(wincl, off, 64);
            if (lane >= off) wincl += t;
        }
        wbase[lane] = wincl - wv_v;
        if (lane == 15)   // publish block total (+1 so 0 means not-ready)
            __hip_atomic_store(&pf[b], wincl + 1, __ATOMIC_RELEASE,
                               __HIP_MEMORY_SCOPE_AGENT);
    }
    if (wv == 0) {
        int val = 0;
        while (true) {
            if (lane < SCAN_BLOCKS && val == 0)
                val = __hip_atomic_load(&pf[lane], __ATOMIC_ACQUIRE,
                                        __HIP_MEMORY_SCOPE_AGENT);
            if (__ballot(lane < SCAN_BLOCKS && val == 0) == 0ull) break;
            __builtin_amdgcn_s_sleep(1);
        }
        int pv = (lane < SCAN_BLOCKS) ? val - 1 : 0;
        int ex = pv;
        #pragma unroll
        for (int off = 1; off < 64; off <<= 1) {
            int t = __shfl_up(ex, off, 64);
            if (lane >= off) ex += t;
        }
        ex -= pv;                     // exclusive prefix of block totals
        if (lane == b) base_s = ex;
    }
    __syncthreads();
    if (i < NN) {
        const int o = base_s + wbase[wv] + incl - v;
        offs[i] = o;
        cursor[i] = o;
    }
    if (b == 0 && tid == 0) offs[NN] = NE;
}

// D4: fill CSR adjacency
__global__ __launch_bounds__(256) void fill_k(
    const int* __restrict__ ei, int* __restrict__ cursor,
    int* __restrict__ eidx) {
    __shared__ int f_s;
    const int f_e64 = probe_e64(ei, threadIdx.x, &f_s);
    const int e = blockIdx.x * 256 + threadIdx.x;
    if (e >= NE) return;
    int s, d;
    if (f_e64) {
        const long long* e64 = (const long long*)ei;
        s = (int)e64[e]; d = (int)e64[NE + e];
    } else {
        s = ei[e]; d = ei[NE + e];
    }
    const int pos = atomicAdd(&cursor[d], 1);
    eidx[pos] = s;
}

// D5/D7: aggregation (nprobe = n1 always; noise1/noise2 share dtype)
__global__ __launch_bounds__(256) void agg_k(
    const int* __restrict__ offs, const int* __restrict__ eidx,
    const uint2* __restrict__ featu2, const void* __restrict__ noise,
    const unsigned int* __restrict__ nprobe, uint2* __restrict__ aggu2) {
    __shared__ int f_s;
    const int f_nb = probe_bf16(nprobe, threadIdx.x, &f_s);
    const int node = (blockIdx.x * 256 + threadIdx.x) >> 6;
    const int lane = threadIdx.x & 63;
    if (node >= NN) return;
    agg_phase(offs, eidx, featu2, noise, f_nb, aggu2, node, lane);
}

// D6/D8: MFMA GEMM (verified round-1 body)
template<bool LAYER1>
__global__ __launch_bounds__(256) void gemm_k(
    const unsigned short* __restrict__ aggb,
    const unsigned short* __restrict__ Wb,
    const unsigned short* __restrict__ bb,
    unsigned short* __restrict__ featb,
    float* __restrict__ outf) {
    __shared__ unsigned short Wl[128 * 136];   // +8 pad: kills quad bank conflict
    __shared__ unsigned short bl[128];
    const int t = threadIdx.x;
    #pragma unroll
    for (int i = 0; i < 8; ++i) {
        const int idx8 = t + i * 256;
        const int base = idx8 * 8;
        const int row = base >> 7, col = base & 127;
        *(uint4*)&Wl[row * 136 + col] = ((const uint4*)Wb)[idx8];
    }
    if (t < 128) bl[t] = bb[t];

    const int lane = t & 63;
    const int w = t >> 6;
    const int n15 = lane & 15;
    const int quad = lane >> 4;
    const int rbase = blockIdx.x * 64 + w * 16;

    bf16x8 af[4];
    #pragma unroll
    for (int kc = 0; kc < 4; ++kc)
        af[kc] = *(const bf16x8*)&aggb[(size_t)(rbase + n15) * DD + kc * 32 + quad * 8];

    __syncthreads();

    float h[32];
    #pragma unroll
    for (int nt = 0; nt < 8; ++nt) {
        f32x4 acc = {0.f, 0.f, 0.f, 0.f};
        #pragma unroll
        for (int kc = 0; kc < 4; ++kc) {
            const bf16x8 bfr =
                *(const bf16x8*)&Wl[(nt * 16 + n15) * 136 + kc * 32 + quad * 8];
            acc = __builtin_amdgcn_mfma_f32_16x16x32_bf16(af[kc], bfr, acc, 0, 0, 0);
        }
        const float bj = bf2f((unsigned int)bl[nt * 16 + n15]);
        #pragma unroll
        for (int r = 0; r < 4; ++r) h[nt * 4 + r] = acc[r] + bj;
    }

    if (LAYER1) {
        const float S = 1.0507009873554805f, AL = 1.6732632423543772f;
        float ss[4] = {0.f, 0.f, 0.f, 0.f};
        #pragma unroll
        for (int nt = 0; nt < 8; ++nt)
            #pragma unroll
            for (int r = 0; r < 4; ++r) {
                float v = h[nt * 4 + r];
                v = v > 0.f ? S * v : S * AL * expm1f(v);
                h[nt * 4 + r] = v;
                ss[r] += v * v;
            }
        #pragma unroll
        for (int r = 0; r < 4; ++r) {
            #pragma unroll
            for (int off = 1; off < 16; off <<= 1)
                ss[r] += __shfl_xor(ss[r], off, 64);
        }
        #pragma unroll
        for (int r = 0; r < 4; ++r) {
            const float nr = sqrtf(ss[r]);
            const float sc = nr > 1.f ? 1.f / nr : 1.f;
            const int row = rbase + quad * 4 + r;
            if (row < NN) {
                #pragma unroll
                for (int nt = 0; nt < 8; ++nt)
                    featb[(size_t)row * DD + nt * 16 + n15] =
                        f2bf(h[nt * 4 + r] * sc);
            }
        }
    } else {
        #pragma unroll
        for (int r = 0; r < 4; ++r) {
            const int row = rbase + quad * 4 + r;
            if (row < NN) {
                #pragma unroll
                for (int nt = 0; nt < 8; ++nt)
                    outf[(size_t)row * DD + nt * 16 + n15] = h[nt * 4 + r];
            }
        }
    }
}

extern "C" void kernel_launch(void* const* d_in, const int* in_sizes, int n_in,
                              void* d_out, int out_size, void* d_ws, size_t ws_size,
                              hipStream_t stream) {
    const void* x  = d_in[0];
    const int*  ei = (const int*)d_in[1];
    const void* W1 = d_in[2];
    const void* b1 = d_in[3];
    const void* W2 = d_in[4];
    const void* b2 = d_in[5];
    const void* n1 = d_in[6];
    const void* n2 = d_in[7];

    // ws layout (~16 MB)
    unsigned short* aggb = (unsigned short*)d_ws;        // NPAD*128 bf16
    unsigned short* W1b  = aggb + (size_t)NPAD * DD;
    unsigned short* b1b  = W1b + DD * DD;
    unsigned short* W2b  = b1b + DD;
    unsigned short* b2b  = W2b + DD * DD;
    int* deg    = (int*)(b2b + DD);
    int* offs   = deg + NN;
    int* cursor = offs + NN + 1;
    int* pf     = cursor + NN;
    int* eidx   = pf + 64;
    unsigned int* featu = (unsigned int*)d_out;

    // D1: probe + convert + zero + prep
    setup_k<<<SETUP_BLOCKS, 256, 0, stream>>>(
        x, W1, b1, W2, b2, W1b, b1b, W2b, b2b, deg, pf, featu);
    // D2-D4: CSR build
    hist_k<<<EDGE_BLOCKS, 256, 0, stream>>>(ei, deg);
    scan_k<<<SCAN_BLOCKS, 1024, 0, stream>>>(deg, offs, cursor, pf);
    fill_k<<<EDGE_BLOCKS, 256, 0, stream>>>(ei, cursor, eidx);
    // D5-D6: layer 1
    agg_k<<<(NN * 64) / 256, 256, 0, stream>>>(offs, eidx, (const uint2*)featu,
                                               n1, (const unsigned int*)n1,
                                               (uint2*)aggb);
    gemm_k<true><<<NTILE, 256, 0, stream>>>(aggb, W1b, b1b,
                                            (unsigned short*)featu, nullptr);
    // D7-D8: layer 2
    agg_k<<<(NN * 64) / 256, 256, 0, stream>>>(offs, eidx, (const uint2*)featu,
                                               n2, (const unsigned int*)n1,
                                               (uint2*)aggb);
    gemm_k<false><<<NTILE, 256, 0, stream>>>(aggb, W2b, b2b, nullptr,
                                             (float*)d_out);
}